// Round 12
// baseline (136.289 us; speedup 1.0000x reference)
//
#include <hip/hip_runtime.h>
#include <cmath>

#define NS 88
#define NL 10
#define NT 30
#define NE 768
#define NH 64
#define NG 256   // 4*H
#define NM 300   // L*T

typedef _Float16 half_t;
typedef __attribute__((ext_vector_type(2))) _Float16 half2_t;
typedef __attribute__((ext_vector_type(8))) _Float16 half8;
typedef __attribute__((ext_vector_type(4))) _Float16 half4v;
typedef __attribute__((ext_vector_type(4))) float f32x4;

__device__ inline void gload_lds16(const void* g, void* l) {
  __builtin_amdgcn_global_load_lds(
      (const __attribute__((address_space(1))) unsigned int*)g,
      (__attribute__((address_space(3))) unsigned int*)l, 16, 0, 0);
}

// fast sigmoid/tanh: v_exp_f32 + v_rcp_f32
__device__ inline float fsigmoid(float x) {
  return __builtin_amdgcn_rcpf(1.f + __expf(-x));
}
__device__ inline float ftanh(float x) {
  float e = __expf(2.f * x);
  return 1.f - 2.f * __builtin_amdgcn_rcpf(e + 1.f);
}

#if __has_builtin(__builtin_amdgcn_fdot2)
__device__ inline float fdot2(half2_t a, half2_t b, float c) {
  return __builtin_amdgcn_fdot2(a, b, c, false);   // v_dot2_f32_f16
}
#else
__device__ inline float fdot2(half2_t a, half2_t b, float c) {
  return fmaf((float)a[1], (float)b[1], fmaf((float)a[0], (float)b[0], c));
}
#endif

__device__ inline half2_t mk_h2(float a, float b) {
  half2_t r; r[0] = (half_t)a; r[1] = (half_t)b; return r;
}

// ---------------------------------------------------------------------------
// convB: Uall_w fp32 [S,768,256] -> fp16 transposed [S,256,768] (n-major,
// k contiguous). LDS 32x32 tile transpose. Grid: S * 24 * 8 blocks.
// ---------------------------------------------------------------------------
__global__ __launch_bounds__(256) void convB_kernel(
    const float* __restrict__ in, half_t* __restrict__ out)
{
  __shared__ float tile[32][36];
  int b  = blockIdx.x;
  int s  = b / 192;
  int r  = b % 192;
  int kt = r / 8;
  int nt = r % 8;
  int t  = threadIdx.x;

  int kk  = t >> 3;
  int nn4 = (t & 7) * 4;
  float4 v = *(const float4*)(in + ((size_t)s * NE + kt * 32 + kk) * NG + nt * 32 + nn4);
  tile[kk][nn4 + 0] = v.x; tile[kk][nn4 + 1] = v.y;
  tile[kk][nn4 + 2] = v.z; tile[kk][nn4 + 3] = v.w;
  __syncthreads();

  int nn = t >> 3;
  int kq = (t & 7) * 4;
  half4v o;
#pragma unroll
  for (int j = 0; j < 4; ++j) o[j] = (half_t)tile[kq + j][nn];
  *(half4v*)(out + ((size_t)s * NG + nt * 32 + nn) * NE + kt * 32 + kq) = o;
}

// ---------------------------------------------------------------------------
// MEGAKERNEL: per (stock, day) block computes its own u-tile via MFMA
// (u never touches global), then wave 0 runs the barrier-free TimeLSTM scan
// + text attention in the same block.
//   GEMM phase (4 waves): 12 k-steps; A = text[bid] 32rows x 64k, f32 load ->
//   f16 cvt -> XOR-swizzled ds_write (R7-proven); B = Bf16[s] 256rows x 64k
//   via 8 global_load_lds (inverse-swizzled per-lane source, linear dest);
//   wave w owns n-quarter w*64; 16 MFMA/wave/step; epilogue -> u_s + Uall_b.
//   Scan phase (wave 0 only): R7-proven single-wave scan reading u_s in LDS.
// LDS 77KB -> 2 blocks/CU (launch_bounds(256,2) caps VGPR for 2 waves/EU).
// ---------------------------------------------------------------------------
__global__ __launch_bounds__(256, 2) void fused_kernel(
    const float*  __restrict__ text,   // [S,300,768] f32 (= [S,L,T,E])
    const half_t* __restrict__ Bf16,   // [S,256,768] f16 (n-major, k contig)
    const float*  __restrict__ ubias,  // [S,256] Uall_b
    const float* __restrict__ time_in, // [S, L, T]
    const float* __restrict__ Wdw,  const float* __restrict__ Wdb,
    const float* __restrict__ Wallw, const float* __restrict__ Wallb,
    const float* __restrict__ tW1w, const float* __restrict__ tW1b,
    const float* __restrict__ tW2w, const float* __restrict__ tW2b,
    const float* __restrict__ tVw,  const float* __restrict__ tVb,
    float* __restrict__ day_vec)       // [S, L, H]
{
  __shared__ float   u_s[32 * NG];     // 32 KiB (rows 30,31 pad)
  __shared__ uint4   Bbuf4[2048];      // 32 KiB
  __shared__ uint4   Abuf4[256];       // 4 KiB
  __shared__ float   hist[NT][NH];     // 7.5 KiB
  __shared__ float   ts_s[NT];
  __shared__ half2_t h2_s[NH / 2];
  __shared__ half2_t c2_s[NH / 2];
  char* Bbuf = (char*)Bbuf4;
  char* Abuf = (char*)Abuf4;

  int b   = blockIdx.x;
  int bid = (b & 7) * 110 + (b >> 3); // 880=8*110 bijective XCD swizzle:
  int s   = bid / NL;                 // same-stock blocks share an XCD (L2)
  int tid = threadIdx.x;
  int w = tid >> 6, l = tid & 63;
  int lr = l & 15, lk = l >> 4;       // fragment row, k-group

  const float*  At = text + (size_t)bid * NT * NE;  // this (s,l)'s 30x768
  const half_t* Bb = Bf16 + (size_t)s * NG * NE;

  if (tid < NT) ts_s[tid] = time_in[(size_t)bid * NT + tid];

  f32x4 acc[2][4];
#pragma unroll
  for (int i = 0; i < 2; ++i)
#pragma unroll
    for (int j = 0; j < 4; ++j) acc[i][j] = (f32x4){0.f, 0.f, 0.f, 0.f};

  // ---- GEMM phase: u_tile(30x256) = A(30x768) . B^T, 12 k-steps ----
#pragma unroll 1
  for (int step = 0; step < 12; ++step) {
    int k0 = step * 64;
    // B: 256 rows x 64k f16 = 32KB, 8 gload rounds, inverse-swz source
#pragma unroll
    for (int j = 0; j < 8; ++j) {
      int ci  = j * 256 + tid;
      int row = ci >> 3;
      int c   = (ci & 7) ^ (row & 7);
      gload_lds16(Bb + (size_t)row * NE + k0 + c * 8,
                  Bbuf + j * 4096 + w * 1024);
    }
    // A: 32 rows x 64k, one 8-elem chunk per thread, f32->f16, swz ds_write
    {
      int row = tid >> 3, c = tid & 7;
      half8 av;
      if (row < NT) {
        const float* p = At + (size_t)row * NE + k0 + c * 8;
        float4 x = *(const float4*)p;
        float4 y = *(const float4*)(p + 4);
        av[0] = (half_t)x.x; av[1] = (half_t)x.y;
        av[2] = (half_t)x.z; av[3] = (half_t)x.w;
        av[4] = (half_t)y.x; av[5] = (half_t)y.y;
        av[6] = (half_t)y.z; av[7] = (half_t)y.w;
      } else {
#pragma unroll
        for (int q = 0; q < 8; ++q) av[q] = (half_t)0.f;
      }
      *(half8*)(Abuf + row * 128 + ((c ^ (row & 7)) * 16)) = av;
    }
    __syncthreads();   // drains vmcnt (gload) + lgkmcnt (ds_write)

#pragma unroll
    for (int kk = 0; kk < 2; ++kk) {
      half8 af[2], bf[4];
#pragma unroll
      for (int fm = 0; fm < 2; ++fm) {
        int rw = fm * 16 + lr;
        int cc = (kk * 4 + lk) ^ (rw & 7);
        af[fm] = *(const half8*)(Abuf + rw * 128 + cc * 16);
      }
#pragma unroll
      for (int fn = 0; fn < 4; ++fn) {
        int rw = w * 64 + fn * 16 + lr;
        int cc = (kk * 4 + lk) ^ (rw & 7);
        bf[fn] = *(const half8*)(Bbuf + rw * 128 + cc * 16);
      }
#pragma unroll
      for (int fm = 0; fm < 2; ++fm)
#pragma unroll
        for (int fn = 0; fn < 4; ++fn)
          acc[fm][fn] = __builtin_amdgcn_mfma_f32_16x16x32_f16(
              af[fm], bf[fn], acc[fm][fn], 0, 0, 0);
    }
    __syncthreads();
  }

  // epilogue -> u_s (+Uall_b). D row = lk*4+e, col = lr (m89 layout).
#pragma unroll
  for (int fn = 0; fn < 4; ++fn) {
    int col = w * 64 + fn * 16 + lr;
    float bv = ubias[(size_t)s * NG + col];
#pragma unroll
    for (int fm = 0; fm < 2; ++fm) {
      int rbase = fm * 16 + lk * 4;
#pragma unroll
      for (int e = 0; e < 4; ++e) {
        int row = rbase + e;
        if (row < NT) u_s[row * NG + col] = acc[fm][fn][e] + bv;
      }
    }
  }
  __syncthreads();   // u_s visible to wave 0

  // ---- scan + attention phase: wave 0 only (barrier-free, ds-ordered) ----
  if (w != 0) return;
  int j = l;   // lane 0..63

  ((half_t*)h2_s)[j] = (half_t)0.f;
  ((half_t*)c2_s)[j] = (half_t)0.f;

  // weights -> packed f16 pairs in VGPRs
  const float* Wa  = Wallw + (size_t)s * NH * NG;
  const float* Wdp = Wdw   + (size_t)s * NH * NH;
  half2_t wf[32], wi[32], wo[32], wg[32], wd[32];
#pragma unroll
  for (int k2 = 0; k2 < 32; ++k2) {
    wf[k2] = mk_h2(Wa[(2*k2) * NG + j],        Wa[(2*k2+1) * NG + j]);
    wi[k2] = mk_h2(Wa[(2*k2) * NG + 64 + j],   Wa[(2*k2+1) * NG + 64 + j]);
    wo[k2] = mk_h2(Wa[(2*k2) * NG + 128 + j],  Wa[(2*k2+1) * NG + 128 + j]);
    wg[k2] = mk_h2(Wa[(2*k2) * NG + 192 + j],  Wa[(2*k2+1) * NG + 192 + j]);
    wd[k2] = mk_h2(Wdp[(2*k2) * NH + j],       Wdp[(2*k2+1) * NH + j]);
  }
  float bf_ = Wallb[(size_t)s * NG + j];
  float bi_ = Wallb[(size_t)s * NG + 64 + j];
  float bo_ = Wallb[(size_t)s * NG + 128 + j];
  float bg_ = Wallb[(size_t)s * NG + 192 + j];
  float bd_ = Wdb[(size_t)s * NH + j];

  float c_my = 0.f;
  for (int t = 0; t < NT; ++t) {
    float accf = bf_ + u_s[t * NG + j];
    float acci = bi_ + u_s[t * NG + 64 + j];
    float acco = bo_ + u_s[t * NG + 128 + j];
    float accg = bg_ + u_s[t * NG + 192 + j];
    float accd = bd_;
#pragma unroll
    for (int k2 = 0; k2 < 32; ++k2) {
      half2_t hv = h2_s[k2];
      half2_t cv = c2_s[k2];
      accf = fdot2(hv, wf[k2], accf);
      acci = fdot2(hv, wi[k2], acci);
      acco = fdot2(hv, wo[k2], acco);
      accg = fdot2(hv, wg[k2], accg);
      accd = fdot2(cv, wd[k2], accd);
    }
    float f  = fsigmoid(accf);          // reference: all-sigmoid gates
    float ii = fsigmoid(acci);
    float o  = fsigmoid(acco);
    float gg = fsigmoid(accg);
    float cadj = c_my + ftanh(accd) * (ts_s[t] - 1.f);
    float cn = fmaf(f, cadj, ii * gg);
    c_my = cn;
    float hn = o * ftanh(cn);
    ((half_t*)h2_s)[j] = (half_t)hn;
    ((half_t*)c2_s)[j] = (half_t)cn;
    hist[t][j] = hn;                    // keep history in LDS (f32)
  }

  // ---- text attention over T ----
  const float* tW1p = tW1w + (size_t)s * NH * NH;
  const float* tW2p = tW2w + (size_t)s * NH * NH;

  float tw2c[NH];                       // tW2 column j in regs
#pragma unroll
  for (int h = 0; h < NH; ++h) tw2c[h] = tW2p[(size_t)h * NH + j];

  float a1 = tW1b[(size_t)s * NH + j];
  {
    const float4* h4 = (const float4*)&hist[NT - 1][0];
#pragma unroll
    for (int q = 0; q < NH / 4; ++q) {
      float4 v = h4[q];
      a1 = fmaf(v.x, tW1p[(size_t)(4*q+0) * NH + j], a1);
      a1 = fmaf(v.y, tW1p[(size_t)(4*q+1) * NH + j], a1);
      a1 = fmaf(v.z, tW1p[(size_t)(4*q+2) * NH + j], a1);
      a1 = fmaf(v.w, tW1p[(size_t)(4*q+3) * NH + j], a1);
    }
  }
  float b2k = tW2b[(size_t)s * NH + j];
  float tv  = tVw[(size_t)s * NH + j];
  float tvb = tVb[s];

  float sc[NT];
#pragma unroll
  for (int t = 0; t < NT; ++t) {
    float a2 = b2k;
    const float4* h4 = (const float4*)&hist[t][0];
#pragma unroll
    for (int q = 0; q < NH / 4; ++q) {
      float4 v = h4[q];
      a2 = fmaf(v.x, tw2c[4*q+0], a2);
      a2 = fmaf(v.y, tw2c[4*q+1], a2);
      a2 = fmaf(v.z, tw2c[4*q+2], a2);
      a2 = fmaf(v.w, tw2c[4*q+3], a2);
    }
    float v = ftanh(a1 + a2) * tv;
#pragma unroll
    for (int off = 32; off >= 1; off >>= 1) v += __shfl_xor(v, off);
    sc[t] = v + tvb;
  }
  float mx = sc[0];
#pragma unroll
  for (int t = 1; t < NT; ++t) mx = fmaxf(mx, sc[t]);
  float sum = 0.f;
#pragma unroll
  for (int t = 0; t < NT; ++t) { sc[t] = __expf(sc[t] - mx); sum += sc[t]; }
  float inv = __builtin_amdgcn_rcpf(sum);
  float dv = 0.f;
#pragma unroll
  for (int t = 0; t < NT; ++t) dv = fmaf(sc[t] * inv, hist[t][j], dv);
  day_vec[(size_t)bid * NH + j] = dv;
}

// ---------------------------------------------------------------------------
// day LSTM + day attention + pred head. One block per stock.
// ---------------------------------------------------------------------------
__global__ __launch_bounds__(256) void day_head_kernel(
    const float* __restrict__ day_vec, // [S, L, H]
    const float* __restrict__ ihw, const float* __restrict__ ihb,
    const float* __restrict__ hhb,
    const float* __restrict__ dW1w, const float* __restrict__ dW1b,
    const float* __restrict__ dW2w, const float* __restrict__ dW2b,
    const float* __restrict__ dVw,  const float* __restrict__ dVb,
    const float* __restrict__ predw, const float* __restrict__ predb,
    float* __restrict__ out)           // [S]
{
  int s = blockIdx.x;
  int g = threadIdx.x;
  int j = g & 63;
  int q = g >> 6;

  __shared__ float dv_s[NL][NH];
  __shared__ float gl[NL][NG];
  __shared__ float hd[NL][NH];

  for (int i = g; i < NL * NH; i += 256)
    ((float*)dv_s)[i] = day_vec[(size_t)s * NL * NH + i];
  __syncthreads();

  float ihcol[NH];
#pragma unroll
  for (int k = 0; k < NH; ++k)
    ihcol[k] = ihw[((size_t)s * NH + k) * NG + g];
  float bias = ihb[(size_t)s * NG + g] + hhb[(size_t)s * NG + g];

  bool is_gpart = (g >= 128 && g < 192);
  for (int l = 0; l < NL; ++l) {
    float acc = bias;
#pragma unroll
    for (int k = 0; k < NH; ++k) acc = fmaf(dv_s[l][k], ihcol[k], acc);
    gl[l][g] = is_gpart ? ftanh(acc) : fsigmoid(acc);
  }
  __syncthreads();
  for (int l = q; l < NL; l += 4) {
    float cd = gl[l][j] * gl[l][128 + j];       // sig(i)*tanh(g)
    hd[l][j] = gl[l][192 + j] * ftanh(cd);      // sig(o)*tanh(c)
  }
  __syncthreads();

  if (g < 64) {
    int k = g;
    float dw1c[NH], dw2c[NH];
#pragma unroll
    for (int h = 0; h < NH; ++h) {
      dw1c[h] = dW1w[((size_t)s * NH + h) * NH + k];
      dw2c[h] = dW2w[((size_t)s * NH + h) * NH + k];
    }
    float b1 = dW1b[(size_t)s * NH + k];
    float b2 = dW2b[(size_t)s * NH + k];
    float dv = dVw[(size_t)s * NH + k];
    float dvb = dVb[s];

    float sc[NL];
#pragma unroll
    for (int l = 0; l < NL; ++l) {
      float x1 = b1, x2 = b2;
#pragma unroll
      for (int h = 0; h < NH; ++h) {
        x1 = fmaf(hd[l][h], dw1c[h], x1);
        x2 = fmaf(hd[l][h], dw2c[h], x2);
      }
      float v = ftanh(x1 + x2) * dv;
#pragma unroll
      for (int off = 32; off >= 1; off >>= 1) v += __shfl_xor(v, off);
      sc[l] = v + dvb;
    }
    float mx = sc[0];
#pragma unroll
    for (int l = 1; l < NL; ++l) mx = fmaxf(mx, sc[l]);
    float sum = 0.f;
#pragma unroll
    for (int l = 0; l < NL; ++l) { sc[l] = __expf(sc[l] - mx); sum += sc[l]; }
    float inv = __builtin_amdgcn_rcpf(sum);
    float sv = 0.f;
#pragma unroll
    for (int l = 0; l < NL; ++l) sv = fmaf(sc[l] * inv, hd[l][k], sv);

    float p = sv * predw[k];
#pragma unroll
    for (int off = 32; off >= 1; off >>= 1) p += __shfl_xor(p, off);
    if (k == 0) {
      float x = p + predb[0];
      out[s] = (x >= 0.f) ? x : 0.01f * x;
    }
  }
}

// ---------------------------------------------------------------------------
extern "C" void kernel_launch(void* const* d_in, const int* in_sizes, int n_in,
                              void* d_out, int out_size, void* d_ws, size_t ws_size,
                              hipStream_t stream) {
  (void)in_sizes; (void)n_in; (void)out_size; (void)ws_size;

  const float* text    = (const float*)d_in[0];
  const float* time_in = (const float*)d_in[1];
  const float* Wdw     = (const float*)d_in[2];
  const float* Wdb     = (const float*)d_in[3];
  const float* Wallw   = (const float*)d_in[4];
  const float* Wallb   = (const float*)d_in[5];
  const float* Uallw   = (const float*)d_in[6];
  const float* Uallb   = (const float*)d_in[7];
  const float* tW1w    = (const float*)d_in[8];
  const float* tW1b    = (const float*)d_in[9];
  const float* tW2w    = (const float*)d_in[10];
  const float* tW2b    = (const float*)d_in[11];
  const float* tVw     = (const float*)d_in[12];
  const float* tVb     = (const float*)d_in[13];
  const float* ihw     = (const float*)d_in[14];
  const float* ihb     = (const float*)d_in[15];
  const float* hhb     = (const float*)d_in[16];
  const float* dW1w    = (const float*)d_in[17];
  const float* dW1b    = (const float*)d_in[18];
  const float* dW2w    = (const float*)d_in[19];
  const float* dW2b    = (const float*)d_in[20];
  const float* dVw     = (const float*)d_in[21];
  const float* dVb     = (const float*)d_in[22];
  const float* predw   = (const float*)d_in[23];
  const float* predb   = (const float*)d_in[24];

  float* ws      = (float*)d_ws;
  float* day_vec = ws;                                  // S*L*H f32
  half_t* Bf16   = (half_t*)(day_vec + (size_t)NS * NL * NH); // S*256*768 f16

  convB_kernel<<<NS * 192, 256, 0, stream>>>(Uallw, Bf16);
  fused_kernel<<<NS * NL, 256, 0, stream>>>(text, Bf16, Uallb, time_in,
                                            Wdw, Wdb, Wallw, Wallb,
                                            tW1w, tW1b, tW2w, tW2b,
                                            tVw, tVb, day_vec);
  day_head_kernel<<<NS, 256, 0, stream>>>(day_vec, ihw, ihb, hhb,
                                          dW1w, dW1b, dW2w, dW2b, dVw, dVb,
                                          predw, predb, (float*)d_out);
}

// Round 13
// 135.483 us; speedup vs baseline: 1.0059x; 1.0059x over previous
//
#include <hip/hip_runtime.h>
#include <cmath>

#define NS 88
#define NL 10
#define NT 30
#define NE 768
#define NH 64
#define NG 256   // 4*H
#define NM 300   // L*T

typedef _Float16 half_t;
typedef __attribute__((ext_vector_type(2))) _Float16 half2_t;
typedef __attribute__((ext_vector_type(8))) _Float16 half8;
typedef __attribute__((ext_vector_type(4))) _Float16 half4v;
typedef __attribute__((ext_vector_type(4))) float f32x4;

__device__ inline void gload_lds16(const void* g, void* l) {
  __builtin_amdgcn_global_load_lds(
      (const __attribute__((address_space(1))) unsigned int*)g,
      (__attribute__((address_space(3))) unsigned int*)l, 16, 0, 0);
}

// fast sigmoid/tanh: v_exp_f32 + v_rcp_f32
__device__ inline float fsigmoid(float x) {
  return __builtin_amdgcn_rcpf(1.f + __expf(-x));
}
__device__ inline float ftanh(float x) {
  float e = __expf(2.f * x);
  return 1.f - 2.f * __builtin_amdgcn_rcpf(e + 1.f);
}

#if __has_builtin(__builtin_amdgcn_fdot2)
__device__ inline float fdot2(half2_t a, half2_t b, float c) {
  return __builtin_amdgcn_fdot2(a, b, c, false);   // v_dot2_f32_f16
}
#else
__device__ inline float fdot2(half2_t a, half2_t b, float c) {
  return fmaf((float)a[1], (float)b[1], fmaf((float)a[0], (float)b[0], c));
}
#endif

__device__ inline half2_t mk_h2(float a, float b) {
  half2_t r; r[0] = (half_t)a; r[1] = (half_t)b; return r;
}

// ---------------------------------------------------------------------------
// convB: Uall_w fp32 [S,768,256] -> fp16 transposed [S,256,768] (n-major,
// k contiguous). LDS 32x32 tile transpose. Grid: S * 24 * 8 blocks.
// ---------------------------------------------------------------------------
__global__ __launch_bounds__(256) void convB_kernel(
    const float* __restrict__ in, half_t* __restrict__ out)
{
  __shared__ float tile[32][36];
  int b  = blockIdx.x;
  int s  = b / 192;
  int r  = b % 192;
  int kt = r / 8;
  int nt = r % 8;
  int t  = threadIdx.x;

  int kk  = t >> 3;
  int nn4 = (t & 7) * 4;
  float4 v = *(const float4*)(in + ((size_t)s * NE + kt * 32 + kk) * NG + nt * 32 + nn4);
  tile[kk][nn4 + 0] = v.x; tile[kk][nn4 + 1] = v.y;
  tile[kk][nn4 + 2] = v.z; tile[kk][nn4 + 3] = v.w;
  __syncthreads();

  int nn = t >> 3;
  int kq = (t & 7) * 4;
  half4v o;
#pragma unroll
  for (int j = 0; j < 4; ++j) o[j] = (half_t)tile[kq + j][nn];
  *(half4v*)(out + ((size_t)s * NG + nt * 32 + nn) * NE + kt * 32 + kq) = o;
}

// ---------------------------------------------------------------------------
// gemm_mfma v13 — BARRIER-FREE main loop.
// One block per (s,l): phase 1 stages the whole A = text[bid] 30x768 f32
// -> f16 into 48KB LDS (chunk-XOR swizzle, rows 30/31 zero), ONE barrier.
// Phase 2: wave w owns n-cols [64w,64w+64); 24 k-steps of {2 ds_read_b128
// A-frags + 4 global_load_dwordx4 B-frags (direct from L2-resident Bf16)
// + 8 MFMA} with NO barriers — LDS read-only, compiler pipelines freely.
// A is read from HBM exactly once (shared across n via LDS).
// ---------------------------------------------------------------------------
__global__ __launch_bounds__(256, 3) void gemm_mfma_kernel(
    const float*  __restrict__ text,  // [S,300,768] f32 (= [S,L,T,E])
    const half_t* __restrict__ Bf16,  // [S,256,768] f16 (n-major, k contig)
    const float*  __restrict__ ubias, // [S,256]
    float* __restrict__ U)            // [S,300,256]
{
  __shared__ char Albuf[32 * 1536];   // 48 KiB: [32 rows][768 f16], swizzled

  int b   = blockIdx.x;
  int bid = (b & 7) * 110 + (b >> 3); // 880 = 8*110, bijective XCD swizzle:
  int s   = bid / NL;                 // same-stock blocks share an XCD L2
  int tid = threadIdx.x;
  int w = tid >> 6, l = tid & 63;
  int lr = l & 15, lk = l >> 4;       // fragment row, k-group

  const float* At = text + (size_t)bid * NT * NE;   // this (s,l)'s 30x768

  // ---- phase 1: stage A f32 -> f16 LDS, swizzled; rows >= 30 zeroed ----
  // 32*768 elems / 4 per float4 = 6144 slots / 256 thr = 24 per thread.
#pragma unroll
  for (int i = 0; i < 24; ++i) {
    int idx = i * 256 + tid;          // float4 slot
    int e   = idx * 4;                // f32 element index
    int row = e / NE;                 // 0..31
    int col = e % NE;                 // multiple of 4
    half4v hv;
    if (row < NT) {
      float4 v = *(const float4*)(At + (size_t)row * NE + col);
      hv[0] = (half_t)v.x; hv[1] = (half_t)v.y;
      hv[2] = (half_t)v.z; hv[3] = (half_t)v.w;
    } else {
      hv[0] = (half_t)0.f; hv[1] = (half_t)0.f;
      hv[2] = (half_t)0.f; hv[3] = (half_t)0.f;
    }
    int chunk = col >> 3;             // 16B chunk within row, 0..95
    int swz   = (chunk & ~7) | ((chunk & 7) ^ (row & 7));
    *(half4v*)(Albuf + (size_t)row * 1536 + swz * 16 + ((col & 7) ? 8 : 0)) = hv;
  }
  __syncthreads();                    // the ONLY barrier

  // ---- phase 2: barrier-free MFMA loop ----
  int n0 = w * 64;
  const half_t* Bb = Bf16 + ((size_t)s * NG + n0) * NE;

  f32x4 acc[2][4];
#pragma unroll
  for (int i = 0; i < 2; ++i)
#pragma unroll
    for (int j = 0; j < 4; ++j) acc[i][j] = (f32x4){0.f, 0.f, 0.f, 0.f};

#pragma unroll 4
  for (int ks = 0; ks < 24; ++ks) {
    half8 af[2], bf[4];
#pragma unroll
    for (int fm = 0; fm < 2; ++fm) {            // A frags from LDS
      int row   = fm * 16 + lr;
      int chunk = ks * 4 + lk;
      int swz   = (chunk & ~7) | ((chunk & 7) ^ (row & 7));
      af[fm] = *(const half8*)(Albuf + (size_t)row * 1536 + swz * 16);
    }
#pragma unroll
    for (int fn = 0; fn < 4; ++fn) {            // B frags direct from global
      bf[fn] = *(const half8*)(Bb + (size_t)(fn * 16 + lr) * NE +
                               ks * 32 + lk * 8);
    }
#pragma unroll
    for (int fm = 0; fm < 2; ++fm)
#pragma unroll
      for (int fn = 0; fn < 4; ++fn)
        acc[fm][fn] = __builtin_amdgcn_mfma_f32_16x16x32_f16(
            af[fm], bf[fn], acc[fm][fn], 0, 0, 0);
  }

  // epilogue: D row = lk*4+e, col = lr (m89 layout); add bias, f32 store
  float* Ub = U + (size_t)bid * NT * NG;
#pragma unroll
  for (int fn = 0; fn < 4; ++fn) {
    int col = n0 + fn * 16 + lr;
    float bv = ubias[(size_t)s * NG + col];
#pragma unroll
    for (int fm = 0; fm < 2; ++fm) {
      int rbase = fm * 16 + lk * 4;
#pragma unroll
      for (int e = 0; e < 4; ++e) {
        int row = rbase + e;
        if (row < NT) Ub[(size_t)row * NG + col] = acc[fm][fn][e] + bv;
      }
    }
  }
}

// ---------------------------------------------------------------------------
// TimeLSTM + text attention FUSED (R7-proven). One wave per (stock, day).
// u tile staged once via global_load_lds (per-lane source); barrier-free.
// ---------------------------------------------------------------------------
__global__ __launch_bounds__(64) void lstm_attn_kernel(
    const float* __restrict__ u,       // [S, L*T, 256] f32
    const float* __restrict__ time_in, // [S, L, T]
    const float* __restrict__ Wdw,  const float* __restrict__ Wdb,
    const float* __restrict__ Wallw, const float* __restrict__ Wallb,
    const float* __restrict__ tW1w, const float* __restrict__ tW1b,
    const float* __restrict__ tW2w, const float* __restrict__ tW2b,
    const float* __restrict__ tVw,  const float* __restrict__ tVb,
    float* __restrict__ day_vec)       // [S, L, H]
{
  int bid = blockIdx.x;                // s*NL + l
  int s = bid / NL;
  int j = threadIdx.x;                 // 0..63

  __shared__ float   u_s[NT * NG];     // 30 KiB
  __shared__ float   hist[NT][NH];     // 7.5 KiB
  __shared__ float   ts_s[NT];
  __shared__ half2_t h2_s[NH / 2];
  __shared__ half2_t c2_s[NH / 2];

  // stage u tile: 30 rows x 1KB, per-lane source (lane j -> bytes 16j..16j+16)
  const float* u_base = u + (size_t)bid * NT * NG;
#pragma unroll
  for (int i = 0; i < NT; ++i)
    gload_lds16(u_base + i * NG + j * 4, (char*)u_s + i * 1024);

  if (j < NT) ts_s[j] = time_in[(size_t)bid * NT + j];
  ((half_t*)h2_s)[j] = (half_t)0.f;
  ((half_t*)c2_s)[j] = (half_t)0.f;

  // weights -> packed f16 pairs in VGPRs
  const float* Wa  = Wallw + (size_t)s * NH * NG;
  const float* Wdp = Wdw   + (size_t)s * NH * NH;
  half2_t wf[32], wi[32], wo[32], wg[32], wd[32];
#pragma unroll
  for (int k2 = 0; k2 < 32; ++k2) {
    wf[k2] = mk_h2(Wa[(2*k2) * NG + j],        Wa[(2*k2+1) * NG + j]);
    wi[k2] = mk_h2(Wa[(2*k2) * NG + 64 + j],   Wa[(2*k2+1) * NG + 64 + j]);
    wo[k2] = mk_h2(Wa[(2*k2) * NG + 128 + j],  Wa[(2*k2+1) * NG + 128 + j]);
    wg[k2] = mk_h2(Wa[(2*k2) * NG + 192 + j],  Wa[(2*k2+1) * NG + 192 + j]);
    wd[k2] = mk_h2(Wdp[(2*k2) * NH + j],       Wdp[(2*k2+1) * NH + j]);
  }
  float bf = Wallb[(size_t)s * NG + j];
  float bi = Wallb[(size_t)s * NG + 64 + j];
  float bo = Wallb[(size_t)s * NG + 128 + j];
  float bg = Wallb[(size_t)s * NG + 192 + j];
  float bd = Wdb[(size_t)s * NH + j];

  // drain global_load_lds before reading u_s (single wave: no barrier)
  asm volatile("s_waitcnt vmcnt(0)" ::: "memory");

  float c_my = 0.f;
  for (int t = 0; t < NT; ++t) {
    float accf = bf + u_s[t * NG + j];
    float acci = bi + u_s[t * NG + 64 + j];
    float acco = bo + u_s[t * NG + 128 + j];
    float accg = bg + u_s[t * NG + 192 + j];
    float accd = bd;
#pragma unroll
    for (int k2 = 0; k2 < 32; ++k2) {
      half2_t hv = h2_s[k2];
      half2_t cv = c2_s[k2];
      accf = fdot2(hv, wf[k2], accf);
      acci = fdot2(hv, wi[k2], acci);
      acco = fdot2(hv, wo[k2], acco);
      accg = fdot2(hv, wg[k2], accg);
      accd = fdot2(cv, wd[k2], accd);
    }
    float f  = fsigmoid(accf);          // reference: all-sigmoid gates
    float ii = fsigmoid(acci);
    float o  = fsigmoid(acco);
    float gg = fsigmoid(accg);
    float cadj = c_my + ftanh(accd) * (ts_s[t] - 1.f);
    float cn = fmaf(f, cadj, ii * gg);
    c_my = cn;
    float hn = o * ftanh(cn);
    ((half_t*)h2_s)[j] = (half_t)hn;
    ((half_t*)c2_s)[j] = (half_t)cn;
    hist[t][j] = hn;                    // keep history in LDS (f32)
  }

  // ---- text attention over T (same wave; hist complete, ds-ordered) ----
  const float* tW1p = tW1w + (size_t)s * NH * NH;
  const float* tW2p = tW2w + (size_t)s * NH * NH;

  float tw2c[NH];                       // tW2 column j in regs
#pragma unroll
  for (int h = 0; h < NH; ++h) tw2c[h] = tW2p[(size_t)h * NH + j];

  float a1 = tW1b[(size_t)s * NH + j];
  {
    const float4* h4 = (const float4*)&hist[NT - 1][0];
#pragma unroll
    for (int q = 0; q < NH / 4; ++q) {
      float4 v = h4[q];
      a1 = fmaf(v.x, tW1p[(size_t)(4*q+0) * NH + j], a1);
      a1 = fmaf(v.y, tW1p[(size_t)(4*q+1) * NH + j], a1);
      a1 = fmaf(v.z, tW1p[(size_t)(4*q+2) * NH + j], a1);
      a1 = fmaf(v.w, tW1p[(size_t)(4*q+3) * NH + j], a1);
    }
  }
  float b2k = tW2b[(size_t)s * NH + j];
  float tv  = tVw[(size_t)s * NH + j];
  float tvb = tVb[s];

  float sc[NT];
#pragma unroll
  for (int t = 0; t < NT; ++t) {
    float a2 = b2k;
    const float4* h4 = (const float4*)&hist[t][0];
#pragma unroll
    for (int q = 0; q < NH / 4; ++q) {
      float4 v = h4[q];
      a2 = fmaf(v.x, tw2c[4*q+0], a2);
      a2 = fmaf(v.y, tw2c[4*q+1], a2);
      a2 = fmaf(v.z, tw2c[4*q+2], a2);
      a2 = fmaf(v.w, tw2c[4*q+3], a2);
    }
    float v = ftanh(a1 + a2) * tv;
#pragma unroll
    for (int off = 32; off >= 1; off >>= 1) v += __shfl_xor(v, off);
    sc[t] = v + tvb;
  }
  float mx = sc[0];
#pragma unroll
  for (int t = 1; t < NT; ++t) mx = fmaxf(mx, sc[t]);
  float sum = 0.f;
#pragma unroll
  for (int t = 0; t < NT; ++t) { sc[t] = __expf(sc[t] - mx); sum += sc[t]; }
  float inv = __builtin_amdgcn_rcpf(sum);
  float dv = 0.f;
#pragma unroll
  for (int t = 0; t < NT; ++t) dv = fmaf(sc[t] * inv, hist[t][j], dv);
  day_vec[(size_t)bid * NH + j] = dv;
}

// ---------------------------------------------------------------------------
// day LSTM + day attention + pred head. One block per stock.
// ---------------------------------------------------------------------------
__global__ __launch_bounds__(256) void day_head_kernel(
    const float* __restrict__ day_vec, // [S, L, H]
    const float* __restrict__ ihw, const float* __restrict__ ihb,
    const float* __restrict__ hhb,
    const float* __restrict__ dW1w, const float* __restrict__ dW1b,
    const float* __restrict__ dW2w, const float* __restrict__ dW2b,
    const float* __restrict__ dVw,  const float* __restrict__ dVb,
    const float* __restrict__ predw, const float* __restrict__ predb,
    float* __restrict__ out)           // [S]
{
  int s = blockIdx.x;
  int g = threadIdx.x;
  int j = g & 63;
  int q = g >> 6;

  __shared__ float dv_s[NL][NH];
  __shared__ float gl[NL][NG];
  __shared__ float hd[NL][NH];

  for (int i = g; i < NL * NH; i += 256)
    ((float*)dv_s)[i] = day_vec[(size_t)s * NL * NH + i];
  __syncthreads();

  float ihcol[NH];
#pragma unroll
  for (int k = 0; k < NH; ++k)
    ihcol[k] = ihw[((size_t)s * NH + k) * NG + g];
  float bias = ihb[(size_t)s * NG + g] + hhb[(size_t)s * NG + g];

  bool is_gpart = (g >= 128 && g < 192);
  for (int l = 0; l < NL; ++l) {
    float acc = bias;
#pragma unroll
    for (int k = 0; k < NH; ++k) acc = fmaf(dv_s[l][k], ihcol[k], acc);
    gl[l][g] = is_gpart ? ftanh(acc) : fsigmoid(acc);
  }
  __syncthreads();
  for (int l = q; l < NL; l += 4) {
    float cd = gl[l][j] * gl[l][128 + j];       // sig(i)*tanh(g)
    hd[l][j] = gl[l][192 + j] * ftanh(cd);      // sig(o)*tanh(c)
  }
  __syncthreads();

  if (g < 64) {
    int k = g;
    float dw1c[NH], dw2c[NH];
#pragma unroll
    for (int h = 0; h < NH; ++h) {
      dw1c[h] = dW1w[((size_t)s * NH + h) * NH + k];
      dw2c[h] = dW2w[((size_t)s * NH + h) * NH + k];
    }
    float b1 = dW1b[(size_t)s * NH + k];
    float b2 = dW2b[(size_t)s * NH + k];
    float dv = dVw[(size_t)s * NH + k];
    float dvb = dVb[s];

    float sc[NL];
#pragma unroll
    for (int l = 0; l < NL; ++l) {
      float x1 = b1, x2 = b2;
#pragma unroll
      for (int h = 0; h < NH; ++h) {
        x1 = fmaf(hd[l][h], dw1c[h], x1);
        x2 = fmaf(hd[l][h], dw2c[h], x2);
      }
      float v = ftanh(x1 + x2) * dv;
#pragma unroll
      for (int off = 32; off >= 1; off >>= 1) v += __shfl_xor(v, off);
      sc[l] = v + dvb;
    }
    float mx = sc[0];
#pragma unroll
    for (int l = 1; l < NL; ++l) mx = fmaxf(mx, sc[l]);
    float sum = 0.f;
#pragma unroll
    for (int l = 0; l < NL; ++l) { sc[l] = __expf(sc[l] - mx); sum += sc[l]; }
    float inv = __builtin_amdgcn_rcpf(sum);
    float sv = 0.f;
#pragma unroll
    for (int l = 0; l < NL; ++l) sv = fmaf(sc[l] * inv, hd[l][k], sv);

    float p = sv * predw[k];
#pragma unroll
    for (int off = 32; off >= 1; off >>= 1) p += __shfl_xor(p, off);
    if (k == 0) {
      float x = p + predb[0];
      out[s] = (x >= 0.f) ? x : 0.01f * x;
    }
  }
}

// ---------------------------------------------------------------------------
extern "C" void kernel_launch(void* const* d_in, const int* in_sizes, int n_in,
                              void* d_out, int out_size, void* d_ws, size_t ws_size,
                              hipStream_t stream) {
  (void)in_sizes; (void)n_in; (void)out_size; (void)ws_size;

  const float* text    = (const float*)d_in[0];
  const float* time_in = (const float*)d_in[1];
  const float* Wdw     = (const float*)d_in[2];
  const float* Wdb     = (const float*)d_in[3];
  const float* Wallw   = (const float*)d_in[4];
  const float* Wallb   = (const float*)d_in[5];
  const float* Uallw   = (const float*)d_in[6];
  const float* Uallb   = (const float*)d_in[7];
  const float* tW1w    = (const float*)d_in[8];
  const float* tW1b    = (const float*)d_in[9];
  const float* tW2w    = (const float*)d_in[10];
  const float* tW2b    = (const float*)d_in[11];
  const float* tVw     = (const float*)d_in[12];
  const float* tVb     = (const float*)d_in[13];
  const float* ihw     = (const float*)d_in[14];
  const float* ihb     = (const float*)d_in[15];
  const float* hhb     = (const float*)d_in[16];
  const float* dW1w    = (const float*)d_in[17];
  const float* dW1b    = (const float*)d_in[18];
  const float* dW2w    = (const float*)d_in[19];
  const float* dW2b    = (const float*)d_in[20];
  const float* dVw     = (const float*)d_in[21];
  const float* dVb     = (const float*)d_in[22];
  const float* predw   = (const float*)d_in[23];
  const float* predb   = (const float*)d_in[24];

  float* ws      = (float*)d_ws;
  float* u       = ws;                                // S*300*256 f32
  float* day_vec = u + (size_t)NS * NM * NG;          // S*L*H    f32
  half_t* Bf16   = (half_t*)(day_vec + (size_t)NS * NL * NH); // S*256*768 f16

  convB_kernel<<<NS * 192, 256, 0, stream>>>(Uallw, Bf16);
  gemm_mfma_kernel<<<NS * NL, 256, 0, stream>>>(text, Bf16, Uallb, u);
  lstm_attn_kernel<<<NS * NL, 64, 0, stream>>>(u, time_in, Wdw, Wdb,
                                               Wallw, Wallb,
                                               tW1w, tW1b, tW2w, tW2b,
                                               tVw, tVb, day_vec);
  day_head_kernel<<<NS, 256, 0, stream>>>(day_vec, ihw, ihb, hhb,
                                          dW1w, dW1b, dW2w, dW2b, dVw, dVb,
                                          predw, predb, (float*)d_out);
}

// Round 14
// 119.711 us; speedup vs baseline: 1.1385x; 1.1317x over previous
//
#include <hip/hip_runtime.h>
#include <cmath>

#define NS 88
#define NL 10
#define NT 30
#define NE 768
#define NH 64
#define NG 256   // 4*H
#define NM 300   // L*T

typedef _Float16 half_t;
typedef __attribute__((ext_vector_type(2))) _Float16 half2_t;
typedef __attribute__((ext_vector_type(8))) _Float16 half8;
typedef __attribute__((ext_vector_type(4))) _Float16 half4v;
typedef __attribute__((ext_vector_type(4))) float f32x4;

__device__ inline void gload_lds16(const void* g, void* l) {
  __builtin_amdgcn_global_load_lds(
      (const __attribute__((address_space(1))) unsigned int*)g,
      (__attribute__((address_space(3))) unsigned int*)l, 16, 0, 0);
}

// fast sigmoid/tanh: v_exp_f32 + v_rcp_f32
__device__ inline float fsigmoid(float x) {
  return __builtin_amdgcn_rcpf(1.f + __expf(-x));
}
__device__ inline float ftanh(float x) {
  float e = __expf(2.f * x);
  return 1.f - 2.f * __builtin_amdgcn_rcpf(e + 1.f);
}

#if __has_builtin(__builtin_amdgcn_fdot2)
__device__ inline float fdot2(half2_t a, half2_t b, float c) {
  return __builtin_amdgcn_fdot2(a, b, c, false);   // v_dot2_f32_f16
}
#else
__device__ inline float fdot2(half2_t a, half2_t b, float c) {
  return fmaf((float)a[1], (float)b[1], fmaf((float)a[0], (float)b[0], c));
}
#endif

__device__ inline half2_t mk_h2(float a, float b) {
  half2_t r; r[0] = (half_t)a; r[1] = (half_t)b; return r;
}

// ---------------------------------------------------------------------------
// convB: Uall_w fp32 [S,768,256] -> fp16 transposed [S,256,768] (n-major,
// k contiguous). LDS 32x32 tile transpose. Grid: S * 24 * 8 blocks.
// ---------------------------------------------------------------------------
__global__ __launch_bounds__(256) void convB_kernel(
    const float* __restrict__ in, half_t* __restrict__ out)
{
  __shared__ float tile[32][36];
  int b  = blockIdx.x;
  int s  = b / 192;
  int r  = b % 192;
  int kt = r / 8;
  int nt = r % 8;
  int t  = threadIdx.x;

  int kk  = t >> 3;
  int nn4 = (t & 7) * 4;
  float4 v = *(const float4*)(in + ((size_t)s * NE + kt * 32 + kk) * NG + nt * 32 + nn4);
  tile[kk][nn4 + 0] = v.x; tile[kk][nn4 + 1] = v.y;
  tile[kk][nn4 + 2] = v.z; tile[kk][nn4 + 3] = v.w;
  __syncthreads();

  int nn = t >> 3;
  int kq = (t & 7) * 4;
  half4v o;
#pragma unroll
  for (int j = 0; j < 4; ++j) o[j] = (half_t)tile[kq + j][nn];
  *(half4v*)(out + ((size_t)s * NG + nt * 32 + nn) * NE + kt * 32 + kq) = o;
}

// ---------------------------------------------------------------------------
// gemm_mfma v14: 64m x 256n tile — FULL N, so text is read from HBM exactly
// ONCE (in-loop A traffic halves vs R7's 2 n-tiles; diagnosis: A traffic is
// the binding constraint, all scheduling variants R8-R13 failed because they
// kept it constant). R7's proven 2-barrier loop otherwise verbatim.
// 440 blocks (88 x 5 m-tiles), 4 waves (each 64m x 64n, acc 4x4,
// 32 MFMA/step), BK=64, 40KB LDS -> 4 blocks/CU, all blocks co-resident.
// A reg-staged f32->f16 with XOR-swizzled ds_write (chunk c -> c^(row&7));
// B via global_load_lds, inverse-swizzled per-lane source (L2-hot panel).
// ---------------------------------------------------------------------------
__global__ __launch_bounds__(256) void gemm_mfma_kernel(
    const float*  __restrict__ text,  // [S,300,768] f32
    const half_t* __restrict__ Bf16,  // [S,256,768] f16 (n-major, k contig)
    const float*  __restrict__ bias,  // [S,256]
    float* __restrict__ U)            // [S,300,256]
{
  __shared__ uint4 smem4[2560];       // 40 KiB: A 8K @0, B 32K @8192
  char* smem = (char*)smem4;

  int b   = blockIdx.x;
  int swz = (b & 7) * 55 + (b >> 3);  // 440 = 8*55, bijective XCD swizzle
  int s   = swz / 5;
  int m0  = (swz % 5) * 64;           // 5 m-tiles (rows 300..319 zeroed)

  int tid = threadIdx.x;
  int w = tid >> 6, l = tid & 63;
  int lr = l & 15, lk = l >> 4;       // fragment row, k-group

  const float*  At = text + (size_t)s * NM * NE;
  const half_t* Bb = Bf16 + (size_t)s * NG * NE;

  f32x4 acc[4][4];                    // [m-frag][n-frag]
#pragma unroll
  for (int i = 0; i < 4; ++i)
#pragma unroll
    for (int j = 0; j < 4; ++j) acc[i][j] = (f32x4){0.f, 0.f, 0.f, 0.f};

  for (int step = 0; step < 12; ++step) {
    int k0 = step * 64;
    // stage B: 256 rows x 64k f16 = 32KB (8 gload rounds), inverse-swz src
#pragma unroll
    for (int j = 0; j < 8; ++j) {
      int ci  = j * 256 + tid;
      int row = ci >> 3;
      int c   = (ci & 7) ^ (row & 7);
      gload_lds16(Bb + (size_t)row * NE + k0 + c * 8,
                  smem + 8192 + j * 4096 + w * 1024);
    }
    // stage A: 64 rows x 64k, f32 global -> f16 -> swizzled ds_write_b128
#pragma unroll
    for (int j = 0; j < 2; ++j) {
      int idx = j * 256 + tid;
      int row = idx >> 3, c = idx & 7;
      int m   = m0 + row;
      half8 av;
      if (m < NM) {
        const float* p = At + (size_t)m * NE + k0 + c * 8;
        float4 x = *(const float4*)p;
        float4 y = *(const float4*)(p + 4);
        av[0] = (half_t)x.x; av[1] = (half_t)x.y;
        av[2] = (half_t)x.z; av[3] = (half_t)x.w;
        av[4] = (half_t)y.x; av[5] = (half_t)y.y;
        av[6] = (half_t)y.z; av[7] = (half_t)y.w;
      } else {
#pragma unroll
        for (int q = 0; q < 8; ++q) av[q] = (half_t)0.f;
      }
      *(half8*)(smem + row * 128 + ((c ^ (row & 7)) * 16)) = av;
    }
    __syncthreads();   // drains vmcnt (gload) + lgkmcnt (ds_write)

#pragma unroll
    for (int kk = 0; kk < 2; ++kk) {
      half8 af[4], bf[4];
#pragma unroll
      for (int fm = 0; fm < 4; ++fm) {          // A frags: all 64 m rows
        int rw = fm * 16 + lr;
        int cc = (kk * 4 + lk) ^ (rw & 7);
        af[fm] = *(const half8*)(smem + rw * 128 + cc * 16);
      }
#pragma unroll
      for (int fn = 0; fn < 4; ++fn) {          // B frags: wave's n-quarter
        int rw = w * 64 + fn * 16 + lr;
        int cc = (kk * 4 + lk) ^ (rw & 7);
        bf[fn] = *(const half8*)(smem + 8192 + rw * 128 + cc * 16);
      }
#pragma unroll
      for (int fm = 0; fm < 4; ++fm)
#pragma unroll
        for (int fn = 0; fn < 4; ++fn)
          acc[fm][fn] = __builtin_amdgcn_mfma_f32_16x16x32_f16(
              af[fm], bf[fn], acc[fm][fn], 0, 0, 0);
    }
    __syncthreads();
  }

  // epilogue: D row = lk*4+e, col = lr (m89 layout); add bias, f32 store
#pragma unroll
  for (int fn = 0; fn < 4; ++fn) {
    int col = w * 64 + fn * 16 + lr;
    float bv = bias[(size_t)s * NG + col];
#pragma unroll
    for (int fm = 0; fm < 4; ++fm) {
      int mbase = m0 + fm * 16 + lk * 4;
#pragma unroll
      for (int e = 0; e < 4; ++e) {
        int m = mbase + e;
        if (m < NM)
          U[((size_t)s * NM + m) * NG + col] = acc[fm][fn][e] + bv;
      }
    }
  }
}

// ---------------------------------------------------------------------------
// TimeLSTM + text attention FUSED (R7-proven). One wave per (stock, day).
// u tile staged once via global_load_lds (per-lane source); barrier-free.
// ---------------------------------------------------------------------------
__global__ __launch_bounds__(64) void lstm_attn_kernel(
    const float* __restrict__ u,       // [S, L*T, 256] f32
    const float* __restrict__ time_in, // [S, L, T]
    const float* __restrict__ Wdw,  const float* __restrict__ Wdb,
    const float* __restrict__ Wallw, const float* __restrict__ Wallb,
    const float* __restrict__ tW1w, const float* __restrict__ tW1b,
    const float* __restrict__ tW2w, const float* __restrict__ tW2b,
    const float* __restrict__ tVw,  const float* __restrict__ tVb,
    float* __restrict__ day_vec)       // [S, L, H]
{
  int bid = blockIdx.x;                // s*NL + l
  int s = bid / NL;
  int j = threadIdx.x;                 // 0..63

  __shared__ float   u_s[NT * NG];     // 30 KiB
  __shared__ float   hist[NT][NH];     // 7.5 KiB
  __shared__ float   ts_s[NT];
  __shared__ half2_t h2_s[NH / 2];
  __shared__ half2_t c2_s[NH / 2];

  // stage u tile: 30 rows x 1KB, per-lane source (lane j -> bytes 16j..16j+16)
  const float* u_base = u + (size_t)bid * NT * NG;
#pragma unroll
  for (int i = 0; i < NT; ++i)
    gload_lds16(u_base + i * NG + j * 4, (char*)u_s + i * 1024);

  if (j < NT) ts_s[j] = time_in[(size_t)bid * NT + j];
  ((half_t*)h2_s)[j] = (half_t)0.f;
  ((half_t*)c2_s)[j] = (half_t)0.f;

  // weights -> packed f16 pairs in VGPRs
  const float* Wa  = Wallw + (size_t)s * NH * NG;
  const float* Wdp = Wdw   + (size_t)s * NH * NH;
  half2_t wf[32], wi[32], wo[32], wg[32], wd[32];
#pragma unroll
  for (int k2 = 0; k2 < 32; ++k2) {
    wf[k2] = mk_h2(Wa[(2*k2) * NG + j],        Wa[(2*k2+1) * NG + j]);
    wi[k2] = mk_h2(Wa[(2*k2) * NG + 64 + j],   Wa[(2*k2+1) * NG + 64 + j]);
    wo[k2] = mk_h2(Wa[(2*k2) * NG + 128 + j],  Wa[(2*k2+1) * NG + 128 + j]);
    wg[k2] = mk_h2(Wa[(2*k2) * NG + 192 + j],  Wa[(2*k2+1) * NG + 192 + j]);
    wd[k2] = mk_h2(Wdp[(2*k2) * NH + j],       Wdp[(2*k2+1) * NH + j]);
  }
  float bf = Wallb[(size_t)s * NG + j];
  float bi = Wallb[(size_t)s * NG + 64 + j];
  float bo = Wallb[(size_t)s * NG + 128 + j];
  float bg = Wallb[(size_t)s * NG + 192 + j];
  float bd = Wdb[(size_t)s * NH + j];

  // drain global_load_lds before reading u_s (single wave: no barrier)
  asm volatile("s_waitcnt vmcnt(0)" ::: "memory");

  float c_my = 0.f;
  for (int t = 0; t < NT; ++t) {
    float accf = bf + u_s[t * NG + j];
    float acci = bi + u_s[t * NG + 64 + j];
    float acco = bo + u_s[t * NG + 128 + j];
    float accg = bg + u_s[t * NG + 192 + j];
    float accd = bd;
#pragma unroll
    for (int k2 = 0; k2 < 32; ++k2) {
      half2_t hv = h2_s[k2];
      half2_t cv = c2_s[k2];
      accf = fdot2(hv, wf[k2], accf);
      acci = fdot2(hv, wi[k2], acci);
      acco = fdot2(hv, wo[k2], acco);
      accg = fdot2(hv, wg[k2], accg);
      accd = fdot2(cv, wd[k2], accd);
    }
    float f  = fsigmoid(accf);          // reference: all-sigmoid gates
    float ii = fsigmoid(acci);
    float o  = fsigmoid(acco);
    float gg = fsigmoid(accg);
    float cadj = c_my + ftanh(accd) * (ts_s[t] - 1.f);
    float cn = fmaf(f, cadj, ii * gg);
    c_my = cn;
    float hn = o * ftanh(cn);
    ((half_t*)h2_s)[j] = (half_t)hn;
    ((half_t*)c2_s)[j] = (half_t)cn;
    hist[t][j] = hn;                    // keep history in LDS (f32)
  }

  // ---- text attention over T (same wave; hist complete, ds-ordered) ----
  const float* tW1p = tW1w + (size_t)s * NH * NH;
  const float* tW2p = tW2w + (size_t)s * NH * NH;

  float tw2c[NH];                       // tW2 column j in regs
#pragma unroll
  for (int h = 0; h < NH; ++h) tw2c[h] = tW2p[(size_t)h * NH + j];

  float a1 = tW1b[(size_t)s * NH + j];
  {
    const float4* h4 = (const float4*)&hist[NT - 1][0];
#pragma unroll
    for (int q = 0; q < NH / 4; ++q) {
      float4 v = h4[q];
      a1 = fmaf(v.x, tW1p[(size_t)(4*q+0) * NH + j], a1);
      a1 = fmaf(v.y, tW1p[(size_t)(4*q+1) * NH + j], a1);
      a1 = fmaf(v.z, tW1p[(size_t)(4*q+2) * NH + j], a1);
      a1 = fmaf(v.w, tW1p[(size_t)(4*q+3) * NH + j], a1);
    }
  }
  float b2k = tW2b[(size_t)s * NH + j];
  float tv  = tVw[(size_t)s * NH + j];
  float tvb = tVb[s];

  float sc[NT];
#pragma unroll
  for (int t = 0; t < NT; ++t) {
    float a2 = b2k;
    const float4* h4 = (const float4*)&hist[t][0];
#pragma unroll
    for (int q = 0; q < NH / 4; ++q) {
      float4 v = h4[q];
      a2 = fmaf(v.x, tw2c[4*q+0], a2);
      a2 = fmaf(v.y, tw2c[4*q+1], a2);
      a2 = fmaf(v.z, tw2c[4*q+2], a2);
      a2 = fmaf(v.w, tw2c[4*q+3], a2);
    }
    float v = ftanh(a1 + a2) * tv;
#pragma unroll
    for (int off = 32; off >= 1; off >>= 1) v += __shfl_xor(v, off);
    sc[t] = v + tvb;
  }
  float mx = sc[0];
#pragma unroll
  for (int t = 1; t < NT; ++t) mx = fmaxf(mx, sc[t]);
  float sum = 0.f;
#pragma unroll
  for (int t = 0; t < NT; ++t) { sc[t] = __expf(sc[t] - mx); sum += sc[t]; }
  float inv = __builtin_amdgcn_rcpf(sum);
  float dv = 0.f;
#pragma unroll
  for (int t = 0; t < NT; ++t) dv = fmaf(sc[t] * inv, hist[t][j], dv);
  day_vec[(size_t)bid * NH + j] = dv;
}

// ---------------------------------------------------------------------------
// day LSTM + day attention + pred head. One block per stock.
// ---------------------------------------------------------------------------
__global__ __launch_bounds__(256) void day_head_kernel(
    const float* __restrict__ day_vec, // [S, L, H]
    const float* __restrict__ ihw, const float* __restrict__ ihb,
    const float* __restrict__ hhb,
    const float* __restrict__ dW1w, const float* __restrict__ dW1b,
    const float* __restrict__ dW2w, const float* __restrict__ dW2b,
    const float* __restrict__ dVw,  const float* __restrict__ dVb,
    const float* __restrict__ predw, const float* __restrict__ predb,
    float* __restrict__ out)           // [S]
{
  int s = blockIdx.x;
  int g = threadIdx.x;
  int j = g & 63;
  int q = g >> 6;

  __shared__ float dv_s[NL][NH];
  __shared__ float gl[NL][NG];
  __shared__ float hd[NL][NH];

  for (int i = g; i < NL * NH; i += 256)
    ((float*)dv_s)[i] = day_vec[(size_t)s * NL * NH + i];
  __syncthreads();

  float ihcol[NH];
#pragma unroll
  for (int k = 0; k < NH; ++k)
    ihcol[k] = ihw[((size_t)s * NH + k) * NG + g];
  float bias = ihb[(size_t)s * NG + g] + hhb[(size_t)s * NG + g];

  bool is_gpart = (g >= 128 && g < 192);
  for (int l = 0; l < NL; ++l) {
    float acc = bias;
#pragma unroll
    for (int k = 0; k < NH; ++k) acc = fmaf(dv_s[l][k], ihcol[k], acc);
    gl[l][g] = is_gpart ? ftanh(acc) : fsigmoid(acc);
  }
  __syncthreads();
  for (int l = q; l < NL; l += 4) {
    float cd = gl[l][j] * gl[l][128 + j];       // sig(i)*tanh(g)
    hd[l][j] = gl[l][192 + j] * ftanh(cd);      // sig(o)*tanh(c)
  }
  __syncthreads();

  if (g < 64) {
    int k = g;
    float dw1c[NH], dw2c[NH];
#pragma unroll
    for (int h = 0; h < NH; ++h) {
      dw1c[h] = dW1w[((size_t)s * NH + h) * NH + k];
      dw2c[h] = dW2w[((size_t)s * NH + h) * NH + k];
    }
    float b1 = dW1b[(size_t)s * NH + k];
    float b2 = dW2b[(size_t)s * NH + k];
    float dv = dVw[(size_t)s * NH + k];
    float dvb = dVb[s];

    float sc[NL];
#pragma unroll
    for (int l = 0; l < NL; ++l) {
      float x1 = b1, x2 = b2;
#pragma unroll
      for (int h = 0; h < NH; ++h) {
        x1 = fmaf(hd[l][h], dw1c[h], x1);
        x2 = fmaf(hd[l][h], dw2c[h], x2);
      }
      float v = ftanh(x1 + x2) * dv;
#pragma unroll
      for (int off = 32; off >= 1; off >>= 1) v += __shfl_xor(v, off);
      sc[l] = v + dvb;
    }
    float mx = sc[0];
#pragma unroll
    for (int l = 1; l < NL; ++l) mx = fmaxf(mx, sc[l]);
    float sum = 0.f;
#pragma unroll
    for (int l = 0; l < NL; ++l) { sc[l] = __expf(sc[l] - mx); sum += sc[l]; }
    float inv = __builtin_amdgcn_rcpf(sum);
    float sv = 0.f;
#pragma unroll
    for (int l = 0; l < NL; ++l) sv = fmaf(sc[l] * inv, hd[l][k], sv);

    float p = sv * predw[k];
#pragma unroll
    for (int off = 32; off >= 1; off >>= 1) p += __shfl_xor(p, off);
    if (k == 0) {
      float x = p + predb[0];
      out[s] = (x >= 0.f) ? x : 0.01f * x;
    }
  }
}

// ---------------------------------------------------------------------------
extern "C" void kernel_launch(void* const* d_in, const int* in_sizes, int n_in,
                              void* d_out, int out_size, void* d_ws, size_t ws_size,
                              hipStream_t stream) {
  (void)in_sizes; (void)n_in; (void)out_size; (void)ws_size;

  const float* text    = (const float*)d_in[0];
  const float* time_in = (const float*)d_in[1];
  const float* Wdw     = (const float*)d_in[2];
  const float* Wdb     = (const float*)d_in[3];
  const float* Wallw   = (const float*)d_in[4];
  const float* Wallb   = (const float*)d_in[5];
  const float* Uallw   = (const float*)d_in[6];
  const float* Uallb   = (const float*)d_in[7];
  const float* tW1w    = (const float*)d_in[8];
  const float* tW1b    = (const float*)d_in[9];
  const float* tW2w    = (const float*)d_in[10];
  const float* tW2b    = (const float*)d_in[11];
  const float* tVw     = (const float*)d_in[12];
  const float* tVb     = (const float*)d_in[13];
  const float* ihw     = (const float*)d_in[14];
  const float* ihb     = (const float*)d_in[15];
  const float* hhb     = (const float*)d_in[16];
  const float* dW1w    = (const float*)d_in[17];
  const float* dW1b    = (const float*)d_in[18];
  const float* dW2w    = (const float*)d_in[19];
  const float* dW2b    = (const float*)d_in[20];
  const float* dVw     = (const float*)d_in[21];
  const float* dVb     = (const float*)d_in[22];
  const float* predw   = (const float*)d_in[23];
  const float* predb   = (const float*)d_in[24];

  float* ws      = (float*)d_ws;
  float* u       = ws;                                // S*300*256 f32
  float* day_vec = u + (size_t)NS * NM * NG;          // S*L*H    f32
  half_t* Bf16   = (half_t*)(day_vec + (size_t)NS * NL * NH); // S*256*768 f16

  convB_kernel<<<NS * 192, 256, 0, stream>>>(Uallw, Bf16);
  gemm_mfma_kernel<<<NS * 5, 256, 0, stream>>>(text, Bf16, Uallb, u);
  lstm_attn_kernel<<<NS * NL, 64, 0, stream>>>(u, time_in, Wdw, Wdb,
                                               Wallw, Wallb,
                                               tW1w, tW1b, tW2w, tW2b,
                                               tVw, tVb, day_vec);
  day_head_kernel<<<NS, 256, 0, stream>>>(day_vec, ihw, ihb, hhb,
                                          dW1w, dW1b, dW2w, dW2b, dVw, dVb,
                                          predw, predb, (float*)d_out);
}

// Round 15
// 102.195 us; speedup vs baseline: 1.3336x; 1.1714x over previous
//
#include <hip/hip_runtime.h>
#include <cmath>

#define NS 88
#define NL 10
#define NT 30
#define NE 768
#define NH 64
#define NG 256   // 4*H
#define NM 300   // L*T

typedef _Float16 half_t;
typedef __attribute__((ext_vector_type(2))) _Float16 half2_t;
typedef __attribute__((ext_vector_type(8))) _Float16 half8;
typedef __attribute__((ext_vector_type(4))) _Float16 half4v;
typedef __attribute__((ext_vector_type(4))) float f32x4;

__device__ inline void gload_lds16(const void* g, void* l) {
  __builtin_amdgcn_global_load_lds(
      (const __attribute__((address_space(1))) unsigned int*)g,
      (__attribute__((address_space(3))) unsigned int*)l, 16, 0, 0);
}

// fast sigmoid/tanh: v_exp_f32 + v_rcp_f32
__device__ inline float fsigmoid(float x) {
  return __builtin_amdgcn_rcpf(1.f + __expf(-x));
}
__device__ inline float ftanh(float x) {
  float e = __expf(2.f * x);
  return 1.f - 2.f * __builtin_amdgcn_rcpf(e + 1.f);
}

#if __has_builtin(__builtin_amdgcn_fdot2)
__device__ inline float fdot2(half2_t a, half2_t b, float c) {
  return __builtin_amdgcn_fdot2(a, b, c, false);   // v_dot2_f32_f16
}
#else
__device__ inline float fdot2(half2_t a, half2_t b, float c) {
  return fmaf((float)a[1], (float)b[1], fmaf((float)a[0], (float)b[0], c));
}
#endif

__device__ inline half2_t mk_h2(float a, float b) {
  half2_t r; r[0] = (half_t)a; r[1] = (half_t)b; return r;
}

// ---------------------------------------------------------------------------
// convB: Uall_w fp32 [S,768,256] -> fp16 transposed [S,256,768] (n-major,
// k contiguous). LDS 32x32 tile transpose. Grid: S * 24 * 8 blocks.
// ---------------------------------------------------------------------------
__global__ __launch_bounds__(256) void convB_kernel(
    const float* __restrict__ in, half_t* __restrict__ out)
{
  __shared__ float tile[32][36];
  int b  = blockIdx.x;
  int s  = b / 192;
  int r  = b % 192;
  int kt = r / 8;
  int nt = r % 8;
  int t  = threadIdx.x;

  int kk  = t >> 3;
  int nn4 = (t & 7) * 4;
  float4 v = *(const float4*)(in + ((size_t)s * NE + kt * 32 + kk) * NG + nt * 32 + nn4);
  tile[kk][nn4 + 0] = v.x; tile[kk][nn4 + 1] = v.y;
  tile[kk][nn4 + 2] = v.z; tile[kk][nn4 + 3] = v.w;
  __syncthreads();

  int nn = t >> 3;
  int kq = (t & 7) * 4;
  half4v o;
#pragma unroll
  for (int j = 0; j < 4; ++j) o[j] = (half_t)tile[kq + j][nn];
  *(half4v*)(out + ((size_t)s * NG + nt * 32 + nn) * NE + kt * 32 + kq) = o;
}

// ---------------------------------------------------------------------------
// gemm_mfma (R14 geometry, f16 output): 64m x 256n tile, text read once.
// 440 blocks (88 x 5 m-tiles), 4 waves (64m x 64n each, acc 4x4), BK=64,
// 40KB LDS -> 4 blocks/CU. u written as f16 (halves write bytes; the
// staged-bytes/eff-BW model says bytes are the binding constraint).
// ---------------------------------------------------------------------------
__global__ __launch_bounds__(256) void gemm_mfma_kernel(
    const float*  __restrict__ text,  // [S,300,768] f32
    const half_t* __restrict__ Bf16,  // [S,256,768] f16 (n-major, k contig)
    const float*  __restrict__ bias,  // [S,256]
    half_t* __restrict__ U)           // [S,300,256] f16
{
  __shared__ uint4 smem4[2560];       // 40 KiB: A 8K @0, B 32K @8192
  char* smem = (char*)smem4;

  int b   = blockIdx.x;
  int swz = (b & 7) * 55 + (b >> 3);  // 440 = 8*55; stock s -> XCD s/11
  int s   = swz / 5;
  int m0  = (swz % 5) * 64;           // 5 m-tiles (rows 300..319 zeroed)

  int tid = threadIdx.x;
  int w = tid >> 6, l = tid & 63;
  int lr = l & 15, lk = l >> 4;       // fragment row, k-group

  const float*  At = text + (size_t)s * NM * NE;
  const half_t* Bb = Bf16 + (size_t)s * NG * NE;

  f32x4 acc[4][4];                    // [m-frag][n-frag]
#pragma unroll
  for (int i = 0; i < 4; ++i)
#pragma unroll
    for (int j = 0; j < 4; ++j) acc[i][j] = (f32x4){0.f, 0.f, 0.f, 0.f};

  for (int step = 0; step < 12; ++step) {
    int k0 = step * 64;
    // stage B: 256 rows x 64k f16 = 32KB (8 gload rounds), inverse-swz src
#pragma unroll
    for (int j = 0; j < 8; ++j) {
      int ci  = j * 256 + tid;
      int row = ci >> 3;
      int c   = (ci & 7) ^ (row & 7);
      gload_lds16(Bb + (size_t)row * NE + k0 + c * 8,
                  smem + 8192 + j * 4096 + w * 1024);
    }
    // stage A: 64 rows x 64k, f32 global -> f16 -> swizzled ds_write_b128
#pragma unroll
    for (int j = 0; j < 2; ++j) {
      int idx = j * 256 + tid;
      int row = idx >> 3, c = idx & 7;
      int m   = m0 + row;
      half8 av;
      if (m < NM) {
        const float* p = At + (size_t)m * NE + k0 + c * 8;
        float4 x = *(const float4*)p;
        float4 y = *(const float4*)(p + 4);
        av[0] = (half_t)x.x; av[1] = (half_t)x.y;
        av[2] = (half_t)x.z; av[3] = (half_t)x.w;
        av[4] = (half_t)y.x; av[5] = (half_t)y.y;
        av[6] = (half_t)y.z; av[7] = (half_t)y.w;
      } else {
#pragma unroll
        for (int q = 0; q < 8; ++q) av[q] = (half_t)0.f;
      }
      *(half8*)(smem + row * 128 + ((c ^ (row & 7)) * 16)) = av;
    }
    __syncthreads();   // drains vmcnt (gload) + lgkmcnt (ds_write)

#pragma unroll
    for (int kk = 0; kk < 2; ++kk) {
      half8 af[4], bf[4];
#pragma unroll
      for (int fm = 0; fm < 4; ++fm) {          // A frags: all 64 m rows
        int rw = fm * 16 + lr;
        int cc = (kk * 4 + lk) ^ (rw & 7);
        af[fm] = *(const half8*)(smem + rw * 128 + cc * 16);
      }
#pragma unroll
      for (int fn = 0; fn < 4; ++fn) {          // B frags: wave's n-quarter
        int rw = w * 64 + fn * 16 + lr;
        int cc = (kk * 4 + lk) ^ (rw & 7);
        bf[fn] = *(const half8*)(smem + 8192 + rw * 128 + cc * 16);
      }
#pragma unroll
      for (int fm = 0; fm < 4; ++fm)
#pragma unroll
        for (int fn = 0; fn < 4; ++fn)
          acc[fm][fn] = __builtin_amdgcn_mfma_f32_16x16x32_f16(
              af[fm], bf[fn], acc[fm][fn], 0, 0, 0);
    }
    __syncthreads();
  }

  // epilogue: D row = lk*4+e, col = lr (m89 layout); add bias, f16 store
#pragma unroll
  for (int fn = 0; fn < 4; ++fn) {
    int col = w * 64 + fn * 16 + lr;
    float bv = bias[(size_t)s * NG + col];
#pragma unroll
    for (int fm = 0; fm < 4; ++fm) {
      int mbase = m0 + fm * 16 + lk * 4;
#pragma unroll
      for (int e = 0; e < 4; ++e) {
        int m = mbase + e;
        if (m < NM)
          U[((size_t)s * NM + m) * NG + col] = (half_t)(acc[fm][fn][e] + bv);
      }
    }
  }
}

// ---------------------------------------------------------------------------
// TimeLSTM + text attention FUSED. One wave per (stock, day), barrier-free.
// u now f16 (15KB stage, halved fetch). XCD swizzle aligned with gemm:
// stock s -> XCD s/11 in both kernels, so u reads hit the local L2.
// ---------------------------------------------------------------------------
__global__ __launch_bounds__(64) void lstm_attn_kernel(
    const half_t* __restrict__ u,      // [S, L*T, 256] f16
    const float* __restrict__ time_in, // [S, L, T]
    const float* __restrict__ Wdw,  const float* __restrict__ Wdb,
    const float* __restrict__ Wallw, const float* __restrict__ Wallb,
    const float* __restrict__ tW1w, const float* __restrict__ tW1b,
    const float* __restrict__ tW2w, const float* __restrict__ tW2b,
    const float* __restrict__ tVw,  const float* __restrict__ tVb,
    float* __restrict__ day_vec)       // [S, L, H]
{
  int b   = blockIdx.x;
  int bid = (b & 7) * 110 + (b >> 3);  // 880 = 8*110; stock s -> XCD s/11
  int s = bid / NL;
  int j = threadIdx.x;                 // 0..63

  __shared__ half_t  u_sh[NT * NG];    // 15 KiB (f16)
  __shared__ float   hist[NT][NH];     // 7.5 KiB
  __shared__ float   ts_s[NT];
  __shared__ half2_t h2_s[NH / 2];
  __shared__ half2_t c2_s[NH / 2];

  // stage u tile: 15 x 1KB (2 rows per gload), per-lane source j*16B
  const half_t* u_base = u + (size_t)bid * NT * NG;
#pragma unroll
  for (int i = 0; i < 15; ++i)
    gload_lds16(u_base + i * 512 + j * 8, (char*)u_sh + i * 1024);

  if (j < NT) ts_s[j] = time_in[(size_t)bid * NT + j];
  ((half_t*)h2_s)[j] = (half_t)0.f;
  ((half_t*)c2_s)[j] = (half_t)0.f;

  // weights -> packed f16 pairs in VGPRs
  const float* Wa  = Wallw + (size_t)s * NH * NG;
  const float* Wdp = Wdw   + (size_t)s * NH * NH;
  half2_t wf[32], wi[32], wo[32], wg[32], wd[32];
#pragma unroll
  for (int k2 = 0; k2 < 32; ++k2) {
    wf[k2] = mk_h2(Wa[(2*k2) * NG + j],        Wa[(2*k2+1) * NG + j]);
    wi[k2] = mk_h2(Wa[(2*k2) * NG + 64 + j],   Wa[(2*k2+1) * NG + 64 + j]);
    wo[k2] = mk_h2(Wa[(2*k2) * NG + 128 + j],  Wa[(2*k2+1) * NG + 128 + j]);
    wg[k2] = mk_h2(Wa[(2*k2) * NG + 192 + j],  Wa[(2*k2+1) * NG + 192 + j]);
    wd[k2] = mk_h2(Wdp[(2*k2) * NH + j],       Wdp[(2*k2+1) * NH + j]);
  }
  float bf = Wallb[(size_t)s * NG + j];
  float bi = Wallb[(size_t)s * NG + 64 + j];
  float bo = Wallb[(size_t)s * NG + 128 + j];
  float bg = Wallb[(size_t)s * NG + 192 + j];
  float bd = Wdb[(size_t)s * NH + j];

  // drain global_load_lds before reading u_sh (single wave: no barrier)
  asm volatile("s_waitcnt vmcnt(0)" ::: "memory");

  float c_my = 0.f;
  for (int t = 0; t < NT; ++t) {
    float accf = bf + (float)u_sh[t * NG + j];
    float acci = bi + (float)u_sh[t * NG + 64 + j];
    float acco = bo + (float)u_sh[t * NG + 128 + j];
    float accg = bg + (float)u_sh[t * NG + 192 + j];
    float accd = bd;
#pragma unroll
    for (int k2 = 0; k2 < 32; ++k2) {
      half2_t hv = h2_s[k2];
      half2_t cv = c2_s[k2];
      accf = fdot2(hv, wf[k2], accf);
      acci = fdot2(hv, wi[k2], acci);
      acco = fdot2(hv, wo[k2], acco);
      accg = fdot2(hv, wg[k2], accg);
      accd = fdot2(cv, wd[k2], accd);
    }
    float f  = fsigmoid(accf);          // reference: all-sigmoid gates
    float ii = fsigmoid(acci);
    float o  = fsigmoid(acco);
    float gg = fsigmoid(accg);
    float cadj = c_my + ftanh(accd) * (ts_s[t] - 1.f);
    float cn = fmaf(f, cadj, ii * gg);
    c_my = cn;
    float hn = o * ftanh(cn);
    ((half_t*)h2_s)[j] = (half_t)hn;
    ((half_t*)c2_s)[j] = (half_t)cn;
    hist[t][j] = hn;                    // keep history in LDS (f32)
  }

  // ---- text attention over T (same wave; hist complete, ds-ordered) ----
  const float* tW1p = tW1w + (size_t)s * NH * NH;
  const float* tW2p = tW2w + (size_t)s * NH * NH;

  float tw2c[NH];                       // tW2 column j in regs
#pragma unroll
  for (int h = 0; h < NH; ++h) tw2c[h] = tW2p[(size_t)h * NH + j];

  float a1 = tW1b[(size_t)s * NH + j];
  {
    const float4* h4 = (const float4*)&hist[NT - 1][0];
#pragma unroll
    for (int q = 0; q < NH / 4; ++q) {
      float4 v = h4[q];
      a1 = fmaf(v.x, tW1p[(size_t)(4*q+0) * NH + j], a1);
      a1 = fmaf(v.y, tW1p[(size_t)(4*q+1) * NH + j], a1);
      a1 = fmaf(v.z, tW1p[(size_t)(4*q+2) * NH + j], a1);
      a1 = fmaf(v.w, tW1p[(size_t)(4*q+3) * NH + j], a1);
    }
  }
  float b2k = tW2b[(size_t)s * NH + j];
  float tv  = tVw[(size_t)s * NH + j];
  float tvb = tVb[s];

  float sc[NT];
#pragma unroll
  for (int t = 0; t < NT; ++t) {
    float a2 = b2k;
    const float4* h4 = (const float4*)&hist[t][0];
#pragma unroll
    for (int q = 0; q < NH / 4; ++q) {
      float4 v = h4[q];
      a2 = fmaf(v.x, tw2c[4*q+0], a2);
      a2 = fmaf(v.y, tw2c[4*q+1], a2);
      a2 = fmaf(v.z, tw2c[4*q+2], a2);
      a2 = fmaf(v.w, tw2c[4*q+3], a2);
    }
    float v = ftanh(a1 + a2) * tv;
#pragma unroll
    for (int off = 32; off >= 1; off >>= 1) v += __shfl_xor(v, off);
    sc[t] = v + tvb;
  }
  float mx = sc[0];
#pragma unroll
  for (int t = 1; t < NT; ++t) mx = fmaxf(mx, sc[t]);
  float sum = 0.f;
#pragma unroll
  for (int t = 0; t < NT; ++t) { sc[t] = __expf(sc[t] - mx); sum += sc[t]; }
  float inv = __builtin_amdgcn_rcpf(sum);
  float dv = 0.f;
#pragma unroll
  for (int t = 0; t < NT; ++t) dv = fmaf(sc[t] * inv, hist[t][j], dv);
  day_vec[(size_t)bid * NH + j] = dv;
}

// ---------------------------------------------------------------------------
// day LSTM + day attention + pred head. One block per stock, XCD-aligned.
// ---------------------------------------------------------------------------
__global__ __launch_bounds__(256) void day_head_kernel(
    const float* __restrict__ day_vec, // [S, L, H]
    const float* __restrict__ ihw, const float* __restrict__ ihb,
    const float* __restrict__ hhb,
    const float* __restrict__ dW1w, const float* __restrict__ dW1b,
    const float* __restrict__ dW2w, const float* __restrict__ dW2b,
    const float* __restrict__ dVw,  const float* __restrict__ dVb,
    const float* __restrict__ predw, const float* __restrict__ predb,
    float* __restrict__ out)           // [S]
{
  int b = blockIdx.x;
  int s = (b & 7) * 11 + (b >> 3);     // 88 = 8*11; stock s -> XCD s/11
  int g = threadIdx.x;
  int j = g & 63;
  int q = g >> 6;

  __shared__ float dv_s[NL][NH];
  __shared__ float gl[NL][NG];
  __shared__ float hd[NL][NH];

  for (int i = g; i < NL * NH; i += 256)
    ((float*)dv_s)[i] = day_vec[(size_t)s * NL * NH + i];
  __syncthreads();

  float ihcol[NH];
#pragma unroll
  for (int k = 0; k < NH; ++k)
    ihcol[k] = ihw[((size_t)s * NH + k) * NG + g];
  float bias = ihb[(size_t)s * NG + g] + hhb[(size_t)s * NG + g];

  bool is_gpart = (g >= 128 && g < 192);
  for (int l = 0; l < NL; ++l) {
    float acc = bias;
#pragma unroll
    for (int k = 0; k < NH; ++k) acc = fmaf(dv_s[l][k], ihcol[k], acc);
    gl[l][g] = is_gpart ? ftanh(acc) : fsigmoid(acc);
  }
  __syncthreads();
  for (int l = q; l < NL; l += 4) {
    float cd = gl[l][j] * gl[l][128 + j];       // sig(i)*tanh(g)
    hd[l][j] = gl[l][192 + j] * ftanh(cd);      // sig(o)*tanh(c)
  }
  __syncthreads();

  if (g < 64) {
    int k = g;
    float dw1c[NH], dw2c[NH];
#pragma unroll
    for (int h = 0; h < NH; ++h) {
      dw1c[h] = dW1w[((size_t)s * NH + h) * NH + k];
      dw2c[h] = dW2w[((size_t)s * NH + h) * NH + k];
    }
    float b1 = dW1b[(size_t)s * NH + k];
    float b2 = dW2b[(size_t)s * NH + k];
    float dv = dVw[(size_t)s * NH + k];
    float dvb = dVb[s];

    float sc[NL];
#pragma unroll
    for (int l = 0; l < NL; ++l) {
      float x1 = b1, x2 = b2;
#pragma unroll
      for (int h = 0; h < NH; ++h) {
        x1 = fmaf(hd[l][h], dw1c[h], x1);
        x2 = fmaf(hd[l][h], dw2c[h], x2);
      }
      float v = ftanh(x1 + x2) * dv;
#pragma unroll
      for (int off = 32; off >= 1; off >>= 1) v += __shfl_xor(v, off);
      sc[l] = v + dvb;
    }
    float mx = sc[0];
#pragma unroll
    for (int l = 1; l < NL; ++l) mx = fmaxf(mx, sc[l]);
    float sum = 0.f;
#pragma unroll
    for (int l = 0; l < NL; ++l) { sc[l] = __expf(sc[l] - mx); sum += sc[l]; }
    float inv = __builtin_amdgcn_rcpf(sum);
    float sv = 0.f;
#pragma unroll
    for (int l = 0; l < NL; ++l) sv = fmaf(sc[l] * inv, hd[l][k], sv);

    float p = sv * predw[k];
#pragma unroll
    for (int off = 32; off >= 1; off >>= 1) p += __shfl_xor(p, off);
    if (k == 0) {
      float x = p + predb[0];
      out[s] = (x >= 0.f) ? x : 0.01f * x;
    }
  }
}

// ---------------------------------------------------------------------------
extern "C" void kernel_launch(void* const* d_in, const int* in_sizes, int n_in,
                              void* d_out, int out_size, void* d_ws, size_t ws_size,
                              hipStream_t stream) {
  (void)in_sizes; (void)n_in; (void)out_size; (void)ws_size;

  const float* text    = (const float*)d_in[0];
  const float* time_in = (const float*)d_in[1];
  const float* Wdw     = (const float*)d_in[2];
  const float* Wdb     = (const float*)d_in[3];
  const float* Wallw   = (const float*)d_in[4];
  const float* Wallb   = (const float*)d_in[5];
  const float* Uallw   = (const float*)d_in[6];
  const float* Uallb   = (const float*)d_in[7];
  const float* tW1w    = (const float*)d_in[8];
  const float* tW1b    = (const float*)d_in[9];
  const float* tW2w    = (const float*)d_in[10];
  const float* tW2b    = (const float*)d_in[11];
  const float* tVw     = (const float*)d_in[12];
  const float* tVb     = (const float*)d_in[13];
  const float* ihw     = (const float*)d_in[14];
  const float* ihb     = (const float*)d_in[15];
  const float* hhb     = (const float*)d_in[16];
  const float* dW1w    = (const float*)d_in[17];
  const float* dW1b    = (const float*)d_in[18];
  const float* dW2w    = (const float*)d_in[19];
  const float* dW2b    = (const float*)d_in[20];
  const float* dVw     = (const float*)d_in[21];
  const float* dVb     = (const float*)d_in[22];
  const float* predw   = (const float*)d_in[23];
  const float* predb   = (const float*)d_in[24];

  float* ws      = (float*)d_ws;
  float* day_vec = ws;                                       // S*L*H f32
  half_t* Bf16   = (half_t*)(day_vec + (size_t)NS * NL * NH);// S*256*768 f16
  half_t* u      = Bf16 + (size_t)NS * NG * NE;              // S*300*256 f16

  convB_kernel<<<NS * 192, 256, 0, stream>>>(Uallw, Bf16);
  gemm_mfma_kernel<<<NS * 5, 256, 0, stream>>>(text, Bf16, Uallb, u);
  lstm_attn_kernel<<<NS * NL, 64, 0, stream>>>(u, time_in, Wdw, Wdb,
                                               Wallw, Wallb,
                                               tW1w, tW1b, tW2w, tW2b,
                                               tVw, tVb, day_vec);
  day_head_kernel<<<NS, 256, 0, stream>>>(day_vec, ihw, ihb, hhb,
                                          dW1w, dW1b, dW2w, dW2b, dVw, dVb,
                                          predw, predb, (float*)d_out);
}